// Round 2
// baseline (103.358 us; speedup 1.0000x reference)
//
#include <hip/hip_runtime.h>
#include <hip/hip_bf16.h>

// GAT layer, algebraically collapsed:
//   u[b,n] = h[b,n,:] . (W @ a[:64])      (row score, == s_i)
//   v[b,n] = h[b,n,:] . (W @ a[64:])      (col score, == s_j)
//   d_i    = sum_j exp(lrelu(u_i+v_j))
//          = e^{u_i} * sum_{v_j > -u_i} e^{v_j}  +  e^{.2 u_i} * sum_{v_j <= -u_i} e^{.2 v_j}
//   c_j    = sum_i exp(lrelu(u_i+v_j)) / d_i
//          = e^{v_j} * sum_{u_i > -v_j} e^{u_i}/d_i + e^{.2 v_j} * sum_{u_i <= -v_j} e^{.2 u_i}/d_i
//   out[b,:] = (1/N) * (sum_j c_j * h[b,j,:]) @ W
// No N x N tensor, no attn@Wh GEMM, no transcendentals in the O(N^2) loops.
// Softmax max-subtraction cancels exactly between numerator/denominator and
// |u|,|v| < ~1.5 (inputs are N(0,1) x 0.05-scaled weights), so exp() is safe.

#define B 8
#define N 2048
#define FIN 128
#define FOUT 64
#define ALPHA 0.2f
#define NSLICE 4      // loop-axis split for pass kernels (512 elems each)
#define SLICE (N / NSLICE)
#define GSLICE 16     // row-slices for the weighted-column-sum kernel

// ---------------- K2: u,v per node (one wave per node, lane holds float2).
// The W@a1 / W@a2 projection (tiny: 128x64) is recomputed per block into LDS.
__global__ __launch_bounds__(256) void k2_uv(const float* __restrict__ h,
                                             const float* __restrict__ W,
                                             const float* __restrict__ a,
                                             float* __restrict__ u, float* __restrict__ v) {
    __shared__ float sw[2 * FIN];
    int t = threadIdx.x;
    if (t < FIN) {
        float wa = 0.f, wb = 0.f;
        for (int f = 0; f < FOUT; ++f) {
            float wk = W[t * FOUT + f];
            wa += wk * a[f];
            wb += wk * a[FOUT + f];
        }
        sw[t] = wa;
        sw[FIN + t] = wb;
    }
    __syncthreads();
    int wave = threadIdx.x >> 6, lane = threadIdx.x & 63;
    int node = blockIdx.x * 4 + wave;  // 0..B*N-1
    const float2 hx = *(const float2*)(h + (size_t)node * FIN + lane * 2);
    const float2 w1x = *(const float2*)(sw + lane * 2);
    const float2 w2x = *(const float2*)(sw + FIN + lane * 2);
    float p1 = hx.x * w1x.x + hx.y * w1x.y;
    float p2 = hx.x * w2x.x + hx.y * w2x.y;
    #pragma unroll
    for (int o = 32; o; o >>= 1) {
        p1 += __shfl_xor(p1, o);
        p2 += __shfl_xor(p2, o);
    }
    if (lane == 0) {
        u[node] = p1;
        v[node] = p2;
    }
}

// ---------------- K3: pass 1 partials. block = (b, i-chunk, j-slice); 256 threads = 256 i's.
__global__ __launch_bounds__(256) void k3_pass1(const float* __restrict__ u,
                                                const float* __restrict__ v,
                                                float* __restrict__ Ap, float* __restrict__ Bp) {
    __shared__ float sv[SLICE], se[SLICE], sf[SLICE];
    int b  = blockIdx.x >> 5;
    int ic = (blockIdx.x >> 2) & 7;
    int js = blockIdx.x & 3;
    int j0 = js * SLICE;
    for (int t = threadIdx.x; t < SLICE; t += 256) {
        float vj = v[b * N + j0 + t];
        sv[t] = vj;
        se[t] = expf(vj);
        sf[t] = expf(ALPHA * vj);
    }
    __syncthreads();
    int i = ic * 256 + threadIdx.x;
    float t = -u[b * N + i];
    float Ax = 0.f, Ay = 0.f, Az = 0.f, Aw = 0.f;
    float Bx = 0.f, By = 0.f, Bz = 0.f, Bw = 0.f;
    for (int j = 0; j < SLICE; j += 4) {
        float4 vv = *(const float4*)&sv[j];
        float4 ee = *(const float4*)&se[j];
        float4 ff = *(const float4*)&sf[j];
        Ax += (vv.x > t) ? ee.x : 0.f;  Bx += (vv.x > t) ? 0.f : ff.x;
        Ay += (vv.y > t) ? ee.y : 0.f;  By += (vv.y > t) ? 0.f : ff.y;
        Az += (vv.z > t) ? ee.z : 0.f;  Bz += (vv.z > t) ? 0.f : ff.z;
        Aw += (vv.w > t) ? ee.w : 0.f;  Bw += (vv.w > t) ? 0.f : ff.w;
    }
    Ap[js * (B * N) + b * N + i] = (Ax + Ay) + (Az + Aw);
    Bp[js * (B * N) + b * N + i] = (Bx + By) + (Bz + Bw);
}

// ---------------- K4: pass 2. block = (b, j-chunk, i-slice); 256 threads = 256 j's.
// Staging computes d_i, r1=e^u/d, r2=e^{.2u}/d on the fly from the pass-1 partials.
__global__ __launch_bounds__(256) void k4_pass2(const float* __restrict__ u,
                                                const float* __restrict__ v,
                                                const float* __restrict__ Ap,
                                                const float* __restrict__ Bp,
                                                float* __restrict__ cp) {
    __shared__ float su[SLICE], sr1[SLICE], sr2[SLICE];
    int b  = blockIdx.x >> 5;
    int jc = (blockIdx.x >> 2) & 7;
    int is = blockIdx.x & 3;
    int i0 = is * SLICE;
    for (int t = threadIdx.x; t < SLICE; t += 256) {
        int ii = b * N + i0 + t;
        float ui = u[ii];
        float A = ((Ap[ii] + Ap[B * N + ii]) + (Ap[2 * B * N + ii] + Ap[3 * B * N + ii]));
        float Bc = ((Bp[ii] + Bp[B * N + ii]) + (Bp[2 * B * N + ii] + Bp[3 * B * N + ii]));
        float eu = expf(ui);
        float fu = expf(ALPHA * ui);
        float d = eu * A + fu * Bc;
        float inv = 1.0f / d;
        su[t] = ui;
        sr1[t] = eu * inv;
        sr2[t] = fu * inv;
    }
    __syncthreads();
    int j = jc * 256 + threadIdx.x;
    float vj = v[b * N + j];
    float t = -vj;
    float Ax = 0.f, Ay = 0.f, Az = 0.f, Aw = 0.f;
    float Bx = 0.f, By = 0.f, Bz = 0.f, Bw = 0.f;
    for (int i = 0; i < SLICE; i += 4) {
        float4 uu = *(const float4*)&su[i];
        float4 r1 = *(const float4*)&sr1[i];
        float4 r2 = *(const float4*)&sr2[i];
        Ax += (uu.x > t) ? r1.x : 0.f;  Bx += (uu.x > t) ? 0.f : r2.x;
        Ay += (uu.y > t) ? r1.y : 0.f;  By += (uu.y > t) ? 0.f : r2.y;
        Az += (uu.z > t) ? r1.z : 0.f;  Bz += (uu.z > t) ? 0.f : r2.z;
        Aw += (uu.w > t) ? r1.w : 0.f;  Bw += (uu.w > t) ? 0.f : r2.w;
    }
    float A = (Ax + Ay) + (Az + Aw);
    float Bc = (Bx + By) + (Bz + Bw);
    cp[is * (B * N) + b * N + j] = expf(vj) * A + expf(ALPHA * vj) * Bc;
}

// ---------------- K5: gp[b,ns,k] = sum_{n in slice} c_n * h[b,n,k]  (128 threads = k)
__global__ __launch_bounds__(128) void k5_g(const float* __restrict__ h,
                                            const float* __restrict__ cp,
                                            float* __restrict__ gp) {
    int b = blockIdx.x >> 4;
    int ns = blockIdx.x & 15;
    int k = threadIdx.x;
    int n0 = ns * (N / GSLICE);
    float acc = 0.f;
    for (int n = 0; n < N / GSLICE; ++n) {
        int nn = b * N + n0 + n;
        float cn = (cp[nn] + cp[B * N + nn]) + (cp[2 * B * N + nn] + cp[3 * B * N + nn]);
        acc += cn * h[(size_t)nn * FIN + k];
    }
    gp[(size_t)blockIdx.x * FIN + k] = acc;
}

// ---------------- K6: out[b,f] = (1/N) * sum_k g[b,k] * W[k,f]
__global__ __launch_bounds__(128) void k6_out(const float* __restrict__ gp,
                                              const float* __restrict__ W,
                                              float* __restrict__ out) {
    __shared__ float sg[FIN];
    int b = blockIdx.x;
    int k = threadIdx.x;
    float g = 0.f;
    for (int s = 0; s < GSLICE; ++s) g += gp[(size_t)(b * GSLICE + s) * FIN + k];
    sg[k] = g;
    __syncthreads();
    if (k < FOUT) {
        float acc = 0.f;
        for (int kk = 0; kk < FIN; ++kk) acc += sg[kk] * W[kk * FOUT + k];
        out[b * FOUT + k] = acc * (1.0f / (float)N);
    }
}

extern "C" void kernel_launch(void* const* d_in, const int* in_sizes, int n_in,
                              void* d_out, int out_size, void* d_ws, size_t ws_size,
                              hipStream_t stream) {
    const float* h = (const float*)d_in[0];  // [B,N,FIN]
    const float* W = (const float*)d_in[1];  // [FIN,FOUT]
    const float* a = (const float*)d_in[2];  // [2*FOUT]
    float* out = (float*)d_out;              // [B,FOUT]

    float* ws = (float*)d_ws;
    float* u   = ws;                   // B*N
    float* v   = u + B * N;            // B*N
    float* Ap  = v + B * N;            // NSLICE*B*N
    float* Bp  = Ap + NSLICE * B * N;  // NSLICE*B*N
    float* cp  = Bp + NSLICE * B * N;  // NSLICE*B*N
    float* gp  = cp + NSLICE * B * N;  // B*GSLICE*FIN

    k2_uv<<<(B * N) / 4, 256, 0, stream>>>(h, W, a, u, v);
    k3_pass1<<<B * 8 * NSLICE, 256, 0, stream>>>(u, v, Ap, Bp);
    k4_pass2<<<B * 8 * NSLICE, 256, 0, stream>>>(u, v, Ap, Bp, cp);
    k5_g<<<B * GSLICE, 128, 0, stream>>>(h, cp, gp);
    k6_out<<<B, FIN, 0, stream>>>(gp, W, out);
}

// Round 4
// 97.196 us; speedup vs baseline: 1.0634x; 1.0634x over previous
//
#include <hip/hip_runtime.h>
#include <hip/hip_bf16.h>

// GAT layer, algebraically collapsed:
//   u[b,n] = h[b,n,:] . (W @ a[:64])      (row score, == s_i)
//   v[b,n] = h[b,n,:] . (W @ a[64:])      (col score, == s_j)
//   d_i    = e^{u_i} * sum_{v_j > -u_i} e^{v_j} + e^{.2 u_i} * sum_{v_j <= -u_i} e^{.2 v_j}
//   c_j    = e^{v_j} * sum_{u_i > -v_j} e^{u_i}/d_i + e^{.2 v_j} * sum_{u_i <= -v_j} e^{.2 u_i}/d_i
//   out[b,:] = (1/N) * (sum_j c_j * h[b,j,:]) @ W
// No N x N tensor, no attn@Wh GEMM, no transcendentals in the O(N^2) loops.
// Pass kernels are register-tiled: each broadcast LDS read feeds 4 rows x 4 cols = 16 pairs.

#define B 8
#define N 2048
#define BN (B * N)
#define FIN 128
#define FOUT 64
#define ALPHA 0.2f

#define JS 16           // j-slices in pass 1 (i-slices in pass 2)
#define SJ (N / JS)     // 128 elements staged in LDS per block
#define IR 4            // rows per thread in pass kernels
#define GS 32           // node-slices in K5

// ---------------- K2: u,v per node. 256 blocks x 256 threads, 64 nodes/block.
// Projection W@a1, W@a2 recomputed per block with COALESCED float4 loads
// (16 threads x float4 per row, shfl-reduce over the 16-lane group).
__global__ __launch_bounds__(256) void k2_uv(const float* __restrict__ h,
                                             const float* __restrict__ W,
                                             const float* __restrict__ a,
                                             float* __restrict__ u, float* __restrict__ v) {
    __shared__ float sa[2 * FOUT];
    __shared__ float sw[2 * FIN];
    int t = threadIdx.x;
    if (t < 2 * FOUT) sa[t] = a[t];
    __syncthreads();
    {
        int kk = t >> 4;          // 0..15: group id (row within pass)
        int f0 = (t & 15) * 4;    // 0..60: f-offset within row
        float a1x = sa[f0], a1y = sa[f0 + 1], a1z = sa[f0 + 2], a1w = sa[f0 + 3];
        float a2x = sa[FOUT + f0], a2y = sa[FOUT + f0 + 1], a2z = sa[FOUT + f0 + 2], a2w = sa[FOUT + f0 + 3];
        #pragma unroll
        for (int p = 0; p < 8; ++p) {
            int k = p * 16 + kk;
            float4 w4 = *(const float4*)(W + k * FOUT + f0);
            float p1 = w4.x * a1x + w4.y * a1y + w4.z * a1z + w4.w * a1w;
            float p2 = w4.x * a2x + w4.y * a2y + w4.z * a2z + w4.w * a2w;
            #pragma unroll
            for (int o = 1; o < 16; o <<= 1) {
                p1 += __shfl_xor(p1, o);
                p2 += __shfl_xor(p2, o);
            }
            if ((t & 15) == 0) { sw[k] = p1; sw[FIN + k] = p2; }
        }
    }
    __syncthreads();
    int wave = t >> 6, lane = t & 63;
    const float2 w1x = *(const float2*)(sw + lane * 2);
    const float2 w2x = *(const float2*)(sw + FIN + lane * 2);
    int node0 = blockIdx.x * 64 + wave * 16;
    for (int it = 0; it < 16; ++it) {
        int node = node0 + it;
        const float2 hx = *(const float2*)(h + (size_t)node * FIN + lane * 2);
        float p1 = hx.x * w1x.x + hx.y * w1x.y;
        float p2 = hx.x * w2x.x + hx.y * w2x.y;
        #pragma unroll
        for (int o = 32; o; o >>= 1) {
            p1 += __shfl_xor(p1, o);
            p2 += __shfl_xor(p2, o);
        }
        if (lane == 0) { u[node] = p1; v[node] = p2; }
    }
}

// ---------------- K3: pass 1 partials. 256 blocks = b(8) x ic(2) x js(16).
// Thread owns IR=4 i-rows; block stages SJ=128 j's in LDS.
__global__ __launch_bounds__(256) void k3_pass1(const float* __restrict__ u,
                                                const float* __restrict__ v,
                                                float* __restrict__ Ap, float* __restrict__ Bp) {
    __shared__ float sv[SJ], se[SJ], sf[SJ];
    int bid = blockIdx.x;
    int b = bid >> 5;
    int ic = (bid >> 4) & 1;
    int js = bid & 15;
    int t = threadIdx.x;
    if (t < SJ) {
        float vj = v[b * N + js * SJ + t];
        sv[t] = vj;
        se[t] = expf(vj);
        sf[t] = expf(ALPHA * vj);
    }
    __syncthreads();
    float th[IR], A[IR], Bm[IR];
    #pragma unroll
    for (int r = 0; r < IR; ++r) {
        th[r] = -u[b * N + ic * 1024 + r * 256 + t];
        A[r] = 0.f; Bm[r] = 0.f;
    }
    for (int j = 0; j < SJ; j += 4) {
        float4 vv = *(const float4*)&sv[j];
        float4 ee = *(const float4*)&se[j];
        float4 ff = *(const float4*)&sf[j];
        #pragma unroll
        for (int r = 0; r < IR; ++r) {
            A[r] += (vv.x > th[r]) ? ee.x : 0.f;  Bm[r] += (vv.x > th[r]) ? 0.f : ff.x;
            A[r] += (vv.y > th[r]) ? ee.y : 0.f;  Bm[r] += (vv.y > th[r]) ? 0.f : ff.y;
            A[r] += (vv.z > th[r]) ? ee.z : 0.f;  Bm[r] += (vv.z > th[r]) ? 0.f : ff.z;
            A[r] += (vv.w > th[r]) ? ee.w : 0.f;  Bm[r] += (vv.w > th[r]) ? 0.f : ff.w;
        }
    }
    #pragma unroll
    for (int r = 0; r < IR; ++r) {
        int i = ic * 1024 + r * 256 + t;
        Ap[js * BN + b * N + i] = A[r];
        Bp[js * BN + b * N + i] = Bm[r];
    }
}

// ---------------- K4: pass 2. 256 blocks = b(8) x jc(2) x is(16).
// Staging sums the 16 pass-1 partials, forms d_i, r1=e^u/d, r2=e^{.2u}/d.
__global__ __launch_bounds__(256) void k4_pass2(const float* __restrict__ u,
                                                const float* __restrict__ v,
                                                const float* __restrict__ Ap,
                                                const float* __restrict__ Bp,
                                                float* __restrict__ cp) {
    __shared__ float su[SJ], sr1[SJ], sr2[SJ];
    int bid = blockIdx.x;
    int b = bid >> 5;
    int jc = (bid >> 4) & 1;
    int is = bid & 15;
    int t = threadIdx.x;
    if (t < SJ) {
        int ii = b * N + is * SJ + t;
        float A = 0.f, Bc = 0.f;
        #pragma unroll
        for (int s = 0; s < 16; ++s) {
            A += Ap[s * BN + ii];
            Bc += Bp[s * BN + ii];
        }
        float ui = u[ii];
        float eu = expf(ui);
        float fu = expf(ALPHA * ui);
        float inv = 1.0f / (eu * A + fu * Bc);
        su[t] = ui;
        sr1[t] = eu * inv;
        sr2[t] = fu * inv;
    }
    __syncthreads();
    float vj[IR], th[IR], Cn[IR], Dn[IR];
    #pragma unroll
    for (int r = 0; r < IR; ++r) {
        vj[r] = v[b * N + jc * 1024 + r * 256 + t];
        th[r] = -vj[r];
        Cn[r] = 0.f; Dn[r] = 0.f;
    }
    for (int i = 0; i < SJ; i += 4) {
        float4 uu = *(const float4*)&su[i];
        float4 r1 = *(const float4*)&sr1[i];
        float4 r2 = *(const float4*)&sr2[i];
        #pragma unroll
        for (int r = 0; r < IR; ++r) {
            Cn[r] += (uu.x > th[r]) ? r1.x : 0.f;  Dn[r] += (uu.x > th[r]) ? 0.f : r2.x;
            Cn[r] += (uu.y > th[r]) ? r1.y : 0.f;  Dn[r] += (uu.y > th[r]) ? 0.f : r2.y;
            Cn[r] += (uu.z > th[r]) ? r1.z : 0.f;  Dn[r] += (uu.z > th[r]) ? 0.f : r2.z;
            Cn[r] += (uu.w > th[r]) ? r1.w : 0.f;  Dn[r] += (uu.w > th[r]) ? 0.f : r2.w;
        }
    }
    #pragma unroll
    for (int r = 0; r < IR; ++r) {
        int j = jc * 1024 + r * 256 + t;
        cp[is * BN + b * N + j] = expf(vj[r]) * Cn[r] + expf(ALPHA * vj[r]) * Dn[r];
    }
}

// ---------------- K5: gp[b,ns,k] = sum_{n in 64-slice} c_n * h[b,n,k].
// 256 blocks x 128 threads (k). c_n reduced from the 16 cp partials into LDS.
__global__ __launch_bounds__(128) void k5_g(const float* __restrict__ h,
                                            const float* __restrict__ cp,
                                            float* __restrict__ gp) {
    __shared__ float sc[64];
    int b = blockIdx.x >> 5;
    int ns = blockIdx.x & 31;
    int t = threadIdx.x;
    if (t < 64) {
        int nn = b * N + ns * 64 + t;
        float c = 0.f;
        #pragma unroll
        for (int s = 0; s < 16; ++s) c += cp[s * BN + nn];
        sc[t] = c;
    }
    __syncthreads();
    float acc = 0.f;
    int base = b * N + ns * 64;
    for (int n = 0; n < 64; ++n)
        acc += sc[n] * h[(size_t)(base + n) * FIN + t];
    gp[(size_t)blockIdx.x * FIN + t] = acc;
}

// ---------------- K6: out[b,f] = (1/N) * sum_k g[b,k] * W[k,f]
__global__ __launch_bounds__(128) void k6_out(const float* __restrict__ gp,
                                              const float* __restrict__ W,
                                              float* __restrict__ out) {
    __shared__ float sg[FIN];
    int b = blockIdx.x;
    int k = threadIdx.x;
    float g = 0.f;
    #pragma unroll
    for (int s = 0; s < GS; ++s) g += gp[(size_t)(b * GS + s) * FIN + k];
    sg[k] = g;
    __syncthreads();
    if (k < FOUT) {
        float acc = 0.f;
        for (int kk = 0; kk < FIN; ++kk) acc += sg[kk] * W[kk * FOUT + k];
        out[b * FOUT + k] = acc * (1.0f / (float)N);
    }
}

extern "C" void kernel_launch(void* const* d_in, const int* in_sizes, int n_in,
                              void* d_out, int out_size, void* d_ws, size_t ws_size,
                              hipStream_t stream) {
    const float* h = (const float*)d_in[0];  // [B,N,FIN]
    const float* W = (const float*)d_in[1];  // [FIN,FOUT]
    const float* a = (const float*)d_in[2];  // [2*FOUT]
    float* out = (float*)d_out;              // [B,FOUT]

    float* ws = (float*)d_ws;
    float* u  = ws;               // BN
    float* v  = u + BN;           // BN
    float* Ap = v + BN;           // JS*BN
    float* Bp = Ap + JS * BN;     // JS*BN
    float* cp = Bp + JS * BN;     // JS*BN
    float* gp = cp + JS * BN;     // B*GS*FIN

    k2_uv<<<BN / 64, 256, 0, stream>>>(h, W, a, u, v);
    k3_pass1<<<256, 256, 0, stream>>>(u, v, Ap, Bp);
    k4_pass2<<<256, 256, 0, stream>>>(u, v, Ap, Bp, cp);
    k5_g<<<256, 128, 0, stream>>>(h, cp, gp);
    k6_out<<<B, FIN, 0, stream>>>(gp, W, out);
}

// Round 5
// 86.209 us; speedup vs baseline: 1.1989x; 1.1274x over previous
//
#include <hip/hip_runtime.h>
#include <hip/hip_bf16.h>

// GAT layer, algebraically collapsed:
//   u[b,n] = h[b,n,:] . (W @ a[:64])      (row score, == s_i)
//   v[b,n] = h[b,n,:] . (W @ a[64:])      (col score, == s_j)
//   d_i    = e^{u_i} * sum_{v_j > -u_i} e^{v_j} + e^{.2 u_i} * sum_{v_j <= -u_i} e^{.2 v_j}
//   c_j    = e^{v_j} * sum_{u_i > -v_j} e^{u_i}/d_i + e^{.2 v_j} * sum_{u_i <= -v_j} e^{.2 u_i}/d_i
//   out[b,:] = (1/N) * (sum_j c_j * h[b,j,:]) @ W
// No N x N tensor, no attn@Wh GEMM, no transcendentals in the O(N^2) loops.
// This round: occupancy fix — all grids sized for >=2 blocks/CU (prev: 1 wave/SIMD,
// latency-exposed). K6 dependency chains broken with unrolled accumulators.

#define B 8
#define N 2048
#define BN (B * N)
#define FIN 128
#define FOUT 64
#define ALPHA 0.2f

#define JS 16           // j-slices in pass 1 (i-slices in pass 2) -> 16 partials
#define SJ (N / JS)     // 128 elements staged in LDS per block
#define IC 4            // i-chunks per batch in pass kernels
#define IR 2            // rows per thread (IC*IR*256 == N)
#define GS 64           // node-slices in K5 (32 rows each)

// ---------------- K2: u,v per node. 1024 blocks x 256 threads, 16 nodes/block
// (4 per wave). Projection W@a1/W@a2 recomputed per block, coalesced float4.
__global__ __launch_bounds__(256) void k2_uv(const float* __restrict__ h,
                                             const float* __restrict__ W,
                                             const float* __restrict__ a,
                                             float* __restrict__ u, float* __restrict__ v) {
    __shared__ float sa[2 * FOUT];
    __shared__ float sw[2 * FIN];
    int t = threadIdx.x;
    if (t < 2 * FOUT) sa[t] = a[t];
    __syncthreads();
    {
        int kk = t >> 4;          // 0..15
        int f0 = (t & 15) * 4;    // 0..60
        float a1x = sa[f0], a1y = sa[f0 + 1], a1z = sa[f0 + 2], a1w = sa[f0 + 3];
        float a2x = sa[FOUT + f0], a2y = sa[FOUT + f0 + 1], a2z = sa[FOUT + f0 + 2], a2w = sa[FOUT + f0 + 3];
        #pragma unroll
        for (int p = 0; p < 8; ++p) {
            int k = p * 16 + kk;
            float4 w4 = *(const float4*)(W + k * FOUT + f0);
            float p1 = w4.x * a1x + w4.y * a1y + w4.z * a1z + w4.w * a1w;
            float p2 = w4.x * a2x + w4.y * a2y + w4.z * a2z + w4.w * a2w;
            #pragma unroll
            for (int o = 1; o < 16; o <<= 1) {
                p1 += __shfl_xor(p1, o);
                p2 += __shfl_xor(p2, o);
            }
            if ((t & 15) == 0) { sw[k] = p1; sw[FIN + k] = p2; }
        }
    }
    __syncthreads();
    int wave = t >> 6, lane = t & 63;
    const float2 w1x = *(const float2*)(sw + lane * 2);
    const float2 w2x = *(const float2*)(sw + FIN + lane * 2);
    int node0 = blockIdx.x * 16 + wave * 4;
    #pragma unroll
    for (int it = 0; it < 4; ++it) {
        int node = node0 + it;
        const float2 hx = *(const float2*)(h + (size_t)node * FIN + lane * 2);
        float p1 = hx.x * w1x.x + hx.y * w1x.y;
        float p2 = hx.x * w2x.x + hx.y * w2x.y;
        #pragma unroll
        for (int o = 32; o; o >>= 1) {
            p1 += __shfl_xor(p1, o);
            p2 += __shfl_xor(p2, o);
        }
        if (lane == 0) { u[node] = p1; v[node] = p2; }
    }
}

// ---------------- K3: pass 1 partials. 512 blocks = b(8) x ic(4) x js(16).
// Thread owns IR=2 i-rows; block stages SJ=128 j's in LDS (uniform broadcasts).
__global__ __launch_bounds__(256) void k3_pass1(const float* __restrict__ u,
                                                const float* __restrict__ v,
                                                float* __restrict__ Ap, float* __restrict__ Bp) {
    __shared__ float sv[SJ], se[SJ], sf[SJ];
    int bid = blockIdx.x;
    int b = bid >> 6;
    int ic = (bid >> 4) & 3;
    int js = bid & 15;
    int t = threadIdx.x;
    if (t < SJ) {
        float vj = v[b * N + js * SJ + t];
        sv[t] = vj;
        se[t] = expf(vj);
        sf[t] = expf(ALPHA * vj);
    }
    __syncthreads();
    float th[IR], A[IR], Bm[IR];
    #pragma unroll
    for (int r = 0; r < IR; ++r) {
        th[r] = -u[b * N + ic * 512 + r * 256 + t];
        A[r] = 0.f; Bm[r] = 0.f;
    }
    for (int j = 0; j < SJ; j += 4) {
        float4 vv = *(const float4*)&sv[j];
        float4 ee = *(const float4*)&se[j];
        float4 ff = *(const float4*)&sf[j];
        #pragma unroll
        for (int r = 0; r < IR; ++r) {
            A[r] += (vv.x > th[r]) ? ee.x : 0.f;  Bm[r] += (vv.x > th[r]) ? 0.f : ff.x;
            A[r] += (vv.y > th[r]) ? ee.y : 0.f;  Bm[r] += (vv.y > th[r]) ? 0.f : ff.y;
            A[r] += (vv.z > th[r]) ? ee.z : 0.f;  Bm[r] += (vv.z > th[r]) ? 0.f : ff.z;
            A[r] += (vv.w > th[r]) ? ee.w : 0.f;  Bm[r] += (vv.w > th[r]) ? 0.f : ff.w;
        }
    }
    #pragma unroll
    for (int r = 0; r < IR; ++r) {
        int i = ic * 512 + r * 256 + t;
        Ap[js * BN + b * N + i] = A[r];
        Bp[js * BN + b * N + i] = Bm[r];
    }
}

// ---------------- K4: pass 2. 512 blocks = b(8) x jc(4) x is(16).
// Staging sums the 16 pass-1 partials, forms d_i, r1=e^u/d, r2=e^{.2u}/d.
__global__ __launch_bounds__(256) void k4_pass2(const float* __restrict__ u,
                                                const float* __restrict__ v,
                                                const float* __restrict__ Ap,
                                                const float* __restrict__ Bp,
                                                float* __restrict__ cp) {
    __shared__ float su[SJ], sr1[SJ], sr2[SJ];
    int bid = blockIdx.x;
    int b = bid >> 6;
    int jc = (bid >> 4) & 3;
    int is = bid & 15;
    int t = threadIdx.x;
    if (t < SJ) {
        int ii = b * N + is * SJ + t;
        float A = 0.f, Bc = 0.f;
        #pragma unroll
        for (int s = 0; s < 16; ++s) {
            A += Ap[s * BN + ii];
            Bc += Bp[s * BN + ii];
        }
        float ui = u[ii];
        float eu = expf(ui);
        float fu = expf(ALPHA * ui);
        float inv = 1.0f / (eu * A + fu * Bc);
        su[t] = ui;
        sr1[t] = eu * inv;
        sr2[t] = fu * inv;
    }
    __syncthreads();
    float vj[IR], th[IR], Cn[IR], Dn[IR];
    #pragma unroll
    for (int r = 0; r < IR; ++r) {
        vj[r] = v[b * N + jc * 512 + r * 256 + t];
        th[r] = -vj[r];
        Cn[r] = 0.f; Dn[r] = 0.f;
    }
    for (int i = 0; i < SJ; i += 4) {
        float4 uu = *(const float4*)&su[i];
        float4 r1 = *(const float4*)&sr1[i];
        float4 r2 = *(const float4*)&sr2[i];
        #pragma unroll
        for (int r = 0; r < IR; ++r) {
            Cn[r] += (uu.x > th[r]) ? r1.x : 0.f;  Dn[r] += (uu.x > th[r]) ? 0.f : r2.x;
            Cn[r] += (uu.y > th[r]) ? r1.y : 0.f;  Dn[r] += (uu.y > th[r]) ? 0.f : r2.y;
            Cn[r] += (uu.z > th[r]) ? r1.z : 0.f;  Dn[r] += (uu.z > th[r]) ? 0.f : r2.z;
            Cn[r] += (uu.w > th[r]) ? r1.w : 0.f;  Dn[r] += (uu.w > th[r]) ? 0.f : r2.w;
        }
    }
    #pragma unroll
    for (int r = 0; r < IR; ++r) {
        int j = jc * 512 + r * 256 + t;
        cp[is * BN + b * N + j] = expf(vj[r]) * Cn[r] + expf(ALPHA * vj[r]) * Dn[r];
    }
}

// ---------------- K5: gp[b,ns,k] = sum_{n in 32-slice} c_n * h[b,n,k].
// 512 blocks x 128 threads (k). c_n reduced from the 16 cp partials into LDS.
__global__ __launch_bounds__(128) void k5_g(const float* __restrict__ h,
                                            const float* __restrict__ cp,
                                            float* __restrict__ gp) {
    __shared__ float sc[32];
    int b = blockIdx.x >> 6;
    int ns = blockIdx.x & 63;
    int t = threadIdx.x;
    if (t < 32) {
        int nn = b * N + ns * 32 + t;
        float c = 0.f;
        #pragma unroll
        for (int s = 0; s < 16; ++s) c += cp[s * BN + nn];
        sc[t] = c;
    }
    __syncthreads();
    float a0 = 0.f, a1 = 0.f, a2 = 0.f, a3 = 0.f;
    int base = b * N + ns * 32;
    #pragma unroll
    for (int n = 0; n < 32; n += 4) {
        a0 += sc[n]     * h[(size_t)(base + n)     * FIN + t];
        a1 += sc[n + 1] * h[(size_t)(base + n + 1) * FIN + t];
        a2 += sc[n + 2] * h[(size_t)(base + n + 2) * FIN + t];
        a3 += sc[n + 3] * h[(size_t)(base + n + 3) * FIN + t];
    }
    gp[(size_t)blockIdx.x * FIN + t] = (a0 + a1) + (a2 + a3);
}

// ---------------- K6: out[b,f] = (1/N) * sum_k g[b,k] * W[k,f]
__global__ __launch_bounds__(128) void k6_out(const float* __restrict__ gp,
                                              const float* __restrict__ W,
                                              float* __restrict__ out) {
    __shared__ float sg[FIN];
    int b = blockIdx.x;
    int k = threadIdx.x;
    float g0 = 0.f, g1 = 0.f, g2 = 0.f, g3 = 0.f;
    #pragma unroll
    for (int s = 0; s < GS; s += 4) {
        g0 += gp[(size_t)(b * GS + s)     * FIN + k];
        g1 += gp[(size_t)(b * GS + s + 1) * FIN + k];
        g2 += gp[(size_t)(b * GS + s + 2) * FIN + k];
        g3 += gp[(size_t)(b * GS + s + 3) * FIN + k];
    }
    sg[k] = (g0 + g1) + (g2 + g3);
    __syncthreads();
    if (k < FOUT) {
        float a0 = 0.f, a1 = 0.f, a2 = 0.f, a3 = 0.f;
        #pragma unroll
        for (int kk = 0; kk < FIN; kk += 4) {
            a0 += sg[kk]     * W[kk * FOUT + k];
            a1 += sg[kk + 1] * W[(kk + 1) * FOUT + k];
            a2 += sg[kk + 2] * W[(kk + 2) * FOUT + k];
            a3 += sg[kk + 3] * W[(kk + 3) * FOUT + k];
        }
        out[b * FOUT + k] = ((a0 + a1) + (a2 + a3)) * (1.0f / (float)N);
    }
}

extern "C" void kernel_launch(void* const* d_in, const int* in_sizes, int n_in,
                              void* d_out, int out_size, void* d_ws, size_t ws_size,
                              hipStream_t stream) {
    const float* h = (const float*)d_in[0];  // [B,N,FIN]
    const float* W = (const float*)d_in[1];  // [FIN,FOUT]
    const float* a = (const float*)d_in[2];  // [2*FOUT]
    float* out = (float*)d_out;              // [B,FOUT]

    float* ws = (float*)d_ws;
    float* u  = ws;               // BN
    float* v  = u + BN;           // BN
    float* Ap = v + BN;           // JS*BN
    float* Bp = Ap + JS * BN;     // JS*BN
    float* cp = Bp + JS * BN;     // JS*BN
    float* gp = cp + JS * BN;     // B*GS*FIN

    k2_uv<<<BN / 16, 256, 0, stream>>>(h, W, a, u, v);
    k3_pass1<<<512, 256, 0, stream>>>(u, v, Ap, Bp);
    k4_pass2<<<512, 256, 0, stream>>>(u, v, Ap, Bp, cp);
    k5_g<<<512, 128, 0, stream>>>(h, cp, gp);
    k6_out<<<B, FIN, 0, stream>>>(gp, W, out);
}